// Round 6
// baseline (98.546 us; speedup 1.0000x reference)
//
#include <hip/hip_runtime.h>
#include <hip/hip_bf16.h>

#define NROWS 8192      // B*T
#define KDIM  768       // F_IN
#define VSZ   320       // V
#define GSZ   2         // G
#define NCOL  640       // G*V
#define DSZ   128       // D
#define BM    32        // rows per tile
#define NMT   (NROWS / BM)             // 256 M-tiles
#define NKB   24                       // K blocks of 32
#define XQ_TOTAL (NROWS * GSZ * DSZ)   // 2097152
#define MARGIN 1.5f
#define XS_STRIDE 776   // 768+8 shorts: 16B-aligned rows, 4-word bank skew

typedef __attribute__((ext_vector_type(8))) short bf16x8;
typedef __attribute__((ext_vector_type(4))) float f32x4;

static __device__ __forceinline__ short f2bf(float f) {
    union { __hip_bfloat16 h; short s; } u;
    u.h = __float2bfloat16(f);   // round-to-nearest-even
    return u.s;
}

// ---------------- W f32 -> packed frag-major bf16 ----------------
// Wb: frag f = nf*24 + kb (nf = 16-col group 0..39, kb = 32-k block 0..23).
// (f, lane): col = nf*16 + (lane&15), k = kb*32 + (lane>>4)*8, 8 bf16.
__global__ __launch_bounds__(512) void prep_w_k(const float* __restrict__ W,
                                                short* __restrict__ Wb) {
    const int idx = blockIdx.x * 512 + threadIdx.x;   // 0..61439
    const int l   = idx & 63;
    const int f   = idx >> 6;
    const int nf  = f / NKB;
    const int kb  = f - nf * NKB;
    const int col = nf * 16 + (l & 15);
    const int k   = kb * 32 + (l >> 4) * 8;
    const float4 a = *(const float4*)(W + (size_t)col * KDIM + k);
    const float4 c = *(const float4*)(W + (size_t)col * KDIM + k + 4);
    bf16x8 r;
    r[0] = f2bf(a.x); r[1] = f2bf(a.y); r[2] = f2bf(a.z); r[3] = f2bf(a.w);
    r[4] = f2bf(c.x); r[5] = f2bf(c.y); r[6] = f2bf(c.z); r[7] = f2bf(c.w);
    *(bf16x8*)(Wb + (size_t)idx * 8) = r;
}

#define LOADB(dst, kb_) do {                                                   \
    _Pragma("unroll")                                                          \
    for (int n = 0; n < 5; ++n)                                                \
        dst[n] = *(const bf16x8*)(Wb + boff[n] + (kb_) * 512);                 \
    } while (0)

#define DOMFMA(src, kb_) do {                                                  \
    const bf16x8 a_ = *(const bf16x8*)&xs[rbase + l15][(kb_) * 32 + l4 * 8];   \
    _Pragma("unroll")                                                          \
    for (int n = 0; n < 5; ++n)                                                \
        acc[n] = __builtin_amdgcn_mfma_f32_16x16x32_bf16(a_, src[n], acc[n], 0, 0, 0); \
    } while (0)

// ---------------- pure GEMM: logits (bf16, bias added) ----------------
// grid 512 = 256 M-tiles x 2 col-halves; 512 threads = 8 waves.
// Wave w: rows rbase..+16 of the 32-row tile, cols (nf0..nf0+5)*16.
__global__ __launch_bounds__(512) void gemm_k(
    const float* __restrict__ x, const short* __restrict__ Wb,
    const float* __restrict__ b, unsigned short* __restrict__ lg) {

    __shared__ short xs[BM][XS_STRIDE];      // 49664 B

    const int tid   = threadIdx.x;
    const int lane  = tid & 63;
    const int w     = tid >> 6;
    const int l15   = lane & 15;
    const int l4    = lane >> 4;
    const int mt    = (int)blockIdx.x >> 1;
    const int h     = (int)blockIdx.x & 1;
    const int row0  = mt * BM;
    const int rbase = (w >> 2) * 16;
    const int nf0   = h * 20 + (w & 3) * 5;

    // stage x tile as bf16: 32 rows x 768 k
    {
        const int srow = tid >> 4;
        const int sk   = (tid & 15) * 4;
        const float* xp = x + (size_t)(row0 + srow) * KDIM + sk;
#pragma unroll
        for (int t = 0; t < 12; ++t) {
            const float4 v = *(const float4*)(xp + t * 64);
            const short t0 = f2bf(v.x), t1 = f2bf(v.y), t2 = f2bf(v.z), t3 = f2bf(v.w);
            const int lo = (t0 & 0xffff) | (t1 << 16);
            const int hi = (t2 & 0xffff) | (t3 << 16);
            *(int2*)&xs[srow][t * 64 + sk] = make_int2(lo, hi);
        }
    }

    int boff[5];
#pragma unroll
    for (int n = 0; n < 5; ++n) boff[n] = ((nf0 + n) * 1536 + lane) * 8;

    f32x4 acc[5];
#pragma unroll
    for (int n = 0; n < 5; ++n) acc[n] = (f32x4){0.f, 0.f, 0.f, 0.f};

    bf16x8 c0[5], c1[5];
    LOADB(c0, 0);
    LOADB(c1, 1);

    __syncthreads();

#pragma unroll 1
    for (int kb = 0; kb < NKB; kb += 2) {
        DOMFMA(c0, kb);
        if (kb + 2 < NKB) { LOADB(c0, kb + 2); __builtin_amdgcn_sched_barrier(0); }
        DOMFMA(c1, kb + 1);
        if (kb + 3 < NKB) { LOADB(c1, kb + 3); __builtin_amdgcn_sched_barrier(0); }
    }

    // store logits (bias folded in)
#pragma unroll
    for (int n = 0; n < 5; ++n) {
        const int col = (nf0 + n) * 16 + l15;
        const float bv = b[col];
#pragma unroll
        for (int r = 0; r < 4; ++r) {
            const int row = row0 + rbase + l4 * 4 + r;
            lg[(size_t)row * NCOL + col] = (unsigned short)f2bf(acc[n][r] + bv);
        }
    }
}

// ---------------- epilogue: argmax + softmax + fp32 refine + gather + partials ----------------
// grid 256 blocks x 512 threads. Block: 32 rows, both groups.
// Wave w: g = w>>2, rows (w&3)*8..+8 — a wave sees ALL 320 cols of its (row,g).
__global__ __launch_bounds__(512) void epi_k(
    const unsigned short* __restrict__ lg, const float* __restrict__ x,
    const float* __restrict__ W, const float* __restrict__ b,
    const float* __restrict__ codebook,
    float* __restrict__ partials,   // [256][1280]: counts(640) then probs(640)
    float* __restrict__ xq) {

    __shared__ float pacc[GSZ][VSZ];
    __shared__ float cnt_f[NCOL];
    __shared__ int   cnt_s[BM][2];
    __shared__ int   list_s[BM][2][16];
    __shared__ int   code_s[BM][2];
    __shared__ int   work_s[64];
    __shared__ int   nwork_s;

    const int tid  = threadIdx.x;
    const int lane = tid & 63;
    const int w    = tid >> 6;
    const int g    = w >> 2;
    const int rset = (w & 3) * 8;
    const int row0 = blockIdx.x * BM;

    for (int i = tid; i < NCOL; i += 512) { cnt_f[i] = 0.f; (&pacc[0][0])[i] = 0.f; }
    if (tid < 64) cnt_s[tid >> 1][tid & 1] = 0;
    if (tid == 0) nwork_s = 0;
    __syncthreads();   // cheap: nothing outstanding

    // upfront loads: 8 rows x 5 cols/lane
    unsigned short lv[8][5];
#pragma unroll
    for (int rr = 0; rr < 8; ++rr)
#pragma unroll
        for (int q = 0; q < 5; ++q)
            lv[rr][q] = lg[(size_t)(row0 + rset + rr) * NCOL + g * VSZ + lane + 64 * q];

    float preg[5] = {0.f, 0.f, 0.f, 0.f, 0.f};

#pragma unroll
    for (int rr = 0; rr < 8; ++rr) {
        const int row = rset + rr;
        float l[5];
        float m = -3.4e38f; int amq = 0;
#pragma unroll
        for (int q = 0; q < 5; ++q) {
            l[q] = __uint_as_float((unsigned)lv[rr][q] << 16);
            if (l[q] > m) { m = l[q]; amq = q; }
        }
        int acol = g * VSZ + lane + 64 * amq;
#pragma unroll
        for (int off = 32; off >= 1; off >>= 1) {
            const float om = __shfl_xor(m, off);
            const int   oc = __shfl_xor(acol, off);
            if (om > m || (om == m && oc < acol)) { m = om; acol = oc; }
        }
        // candidates within margin
#pragma unroll
        for (int q = 0; q < 5; ++q) {
            if (l[q] > m - MARGIN) {
                const int idx = atomicAdd(&cnt_s[row][g], 1);
                if (idx < 16) list_s[row][g][idx] = g * VSZ + lane + 64 * q;
            }
        }
        float s = 0.f; float e[5];
#pragma unroll
        for (int q = 0; q < 5; ++q) { e[q] = __expf(l[q] - m); s += e[q]; }
#pragma unroll
        for (int off = 32; off >= 1; off >>= 1) s += __shfl_xor(s, off);
        const float inv = 1.f / s;
#pragma unroll
        for (int q = 0; q < 5; ++q) preg[q] += e[q] * inv;
        if (lane == 0) {
            code_s[row][g] = acol;
            if (cnt_s[row][g] > 1) {
                const int wi = atomicAdd(&nwork_s, 1);
                work_s[wi] = row * 2 + g;
            }
        }
    }
    __syncthreads();

    // fp32-exact refinement, one wave per pending (row,g)
    const int nwork = nwork_s;
    for (int it = w; it < nwork; it += 8) {
        const int rg  = work_s[it];
        const int row = rg >> 1, gg = rg & 1;
        const int grow = row0 + row;
        const int nc   = min(cnt_s[row][gg], 16);
        float bestv = -3.4e38f; int bestc = 0x7fffffff;
        for (int ci = 0; ci < nc; ++ci) {
            const int col = list_s[row][gg][ci];
            float p = 0.f;
            for (int j = lane; j < KDIM; j += 64)
                p += x[(size_t)grow * KDIM + j] * W[(size_t)col * KDIM + j];
#pragma unroll
            for (int off = 32; off >= 1; off >>= 1) p += __shfl_xor(p, off);
            p += b[col];
            if (p > bestv || (p == bestv && col < bestc)) { bestv = p; bestc = col; }
        }
        if (lane == 0) code_s[row][gg] = bestc;
    }
    __syncthreads();

    // counts histogram + prob col-sums + gather
    if (tid < 64) atomicAdd(&cnt_f[code_s[tid >> 1][tid & 1]], 1.f);
#pragma unroll
    for (int q = 0; q < 5; ++q) atomicAdd(&pacc[g][lane + 64 * q], preg[q]);
#pragma unroll
    for (int u = 0; u < 4; ++u) {
        const int f   = tid + u * 512;      // float4 index 0..2047
        const int row = f >> 6;
        const int c   = f & 63;
        const int gg  = c >> 5;
        const int d4  = (c & 31) * 4;
        const int k   = code_s[row][gg];    // global col = codebook row
        const float4 v = *(const float4*)(codebook + (size_t)k * DSZ + d4);
        *(float4*)(xq + (size_t)(row0 + row) * (GSZ * DSZ) + gg * DSZ + d4) = v;
    }
    __syncthreads();

    float* myp = partials + (size_t)blockIdx.x * (2 * NCOL);
    for (int i = tid; i < 2 * NCOL; i += 512)
        myp[i] = (i < NCOL) ? cnt_f[i] : (&pacc[0][0])[i - NCOL];
}

// ---------------- reduce partials + perplexities + constant ----------------
__global__ __launch_bounds__(640) void red_fin_k(const float* __restrict__ partials,
                                                 float* __restrict__ out_scalars) {
    __shared__ float se_c[GSZ], se_p[GSZ];
    const int t = threadIdx.x;   // 0..639 = column
    if (t < GSZ) { se_c[t] = 0.f; se_p[t] = 0.f; }
    __syncthreads();
    float sc = 0.f, sp = 0.f;
#pragma unroll 8
    for (int m = 0; m < NMT; ++m) {
        sc += partials[(size_t)m * (2 * NCOL) + t];
        sp += partials[(size_t)m * (2 * NCOL) + NCOL + t];
    }
    const int g = t / VSZ;
    const float hp = sc * (1.f / (float)NROWS);
    const float ap = sp * (1.f / (float)NROWS);
    float tc = hp * logf(hp + 1e-7f);
    float tp = ap * logf(ap + 1e-7f);
#pragma unroll
    for (int off = 32; off >= 1; off >>= 1) {
        tc += __shfl_xor(tc, off);
        tp += __shfl_xor(tp, off);
    }
    if ((t & 63) == 0) { atomicAdd(&se_c[g], tc); atomicAdd(&se_p[g], tp); }
    __syncthreads();
    if (t == 0) {
        out_scalars[0] = (float)NCOL;
        out_scalars[1] = expf(-se_c[0]) + expf(-se_c[1]);
        out_scalars[2] = expf(-se_p[0]) + expf(-se_p[1]);
    }
}

extern "C" void kernel_launch(void* const* d_in, const int* in_sizes, int n_in,
                              void* d_out, int out_size, void* d_ws, size_t ws_size,
                              hipStream_t stream) {
    const float* x        = (const float*)d_in[0];
    const float* W        = (const float*)d_in[1];
    const float* b        = (const float*)d_in[2];
    const float* codebook = (const float*)d_in[3];
    float* out = (float*)d_out;

    short*          Wb       = (short*)d_ws;                                   // 983,040 B
    unsigned short* lg       = (unsigned short*)((char*)d_ws + 983040);        // 10,485,760 B
    float*          partials = (float*)((char*)d_ws + 983040 + 10485760);      // 1,310,720 B

    prep_w_k<<<dim3(120), dim3(512), 0, stream>>>(W, Wb);
    gemm_k<<<dim3(NMT * 2), dim3(512), 0, stream>>>(x, Wb, b, lg);
    epi_k<<<dim3(NMT), dim3(512), 0, stream>>>(lg, x, W, b, codebook, partials, out);
    red_fin_k<<<dim3(1), dim3(640), 0, stream>>>(partials, out + XQ_TOTAL);
}

// Round 7
// 64.109 us; speedup vs baseline: 1.5372x; 1.5372x over previous
//
#include <hip/hip_runtime.h>
#include <hip/hip_bf16.h>

#define NROWS 8192      // B*T
#define KDIM  768       // F_IN
#define VSZ   320       // V
#define GSZ   2         // G
#define NCOL  640       // G*V
#define DSZ   128       // D
#define BM    64        // rows per block
#define NMT   (NROWS / BM)             // 128 M-tiles
#define NBLK  (NMT * 2)                // 256 blocks (x2 group-halves)
#define NKB   24                       // K blocks of 32
#define XQ_TOTAL (NROWS * GSZ * DSZ)   // 2097152
#define MARGIN 1.5f
#define XS_STRIDE 776   // 768+8 shorts: 16B-aligned rows, 4-word bank skew

typedef __attribute__((ext_vector_type(8))) short bf16x8;
typedef __attribute__((ext_vector_type(4))) float f32x4;

static __device__ __forceinline__ short f2bf(float f) {
    union { __hip_bfloat16 h; short s; } u;
    u.h = __float2bfloat16(f);   // round-to-nearest-even
    return u.s;
}

// ---------------- W f32 -> packed frag-major bf16 ----------------
// Wb: frag f = nf*24 + kb (nf = 16-col group 0..39, kb = 32-k block 0..23).
// (f, lane): col = nf*16 + (lane&15), k = kb*32 + (lane>>4)*8, 8 bf16.
// A wave's frag load = 64 lanes x 16B contiguous = 1KB stream.
__global__ __launch_bounds__(512) void prep_w_k(const float* __restrict__ W,
                                                short* __restrict__ Wb) {
    const int idx = blockIdx.x * 512 + threadIdx.x;   // 0..61439
    const int l   = idx & 63;
    const int f   = idx >> 6;
    const int nf  = f / NKB;
    const int kb  = f - nf * NKB;
    const int col = nf * 16 + (l & 15);
    const int k   = kb * 32 + (l >> 4) * 8;
    const float4 a = *(const float4*)(W + (size_t)col * KDIM + k);
    const float4 c = *(const float4*)(W + (size_t)col * KDIM + k + 4);
    bf16x8 r;
    r[0] = f2bf(a.x); r[1] = f2bf(a.y); r[2] = f2bf(a.z); r[3] = f2bf(a.w);
    r[4] = f2bf(c.x); r[5] = f2bf(c.y); r[6] = f2bf(c.z); r[7] = f2bf(c.w);
    *(bf16x8*)(Wb + (size_t)idx * 8) = r;
}

#define LOADB(dst, kb_) do {                                                   \
    _Pragma("unroll")                                                          \
    for (int n = 0; n < 5; ++n)                                                \
        dst[n] = *(const bf16x8*)(Wb + boff[n] + (kb_) * 512);                 \
    } while (0)

#define DOMFMA(src, kb_) do {                                                  \
    const bf16x8 a_ = *(const bf16x8*)&xs[rbase + l15][(kb_) * 32 + l4 * 8];   \
    _Pragma("unroll")                                                          \
    for (int n = 0; n < 5; ++n)                                                \
        acc[n] = __builtin_amdgcn_mfma_f32_16x16x32_bf16(a_, src[n], acc[n], 0, 0, 0); \
    } while (0)

// ---------------- fused bf16-MFMA GEMM + argmax + softmax + fp32 refine + gather ----------------
// grid 256 = 128 M-tiles x 2 group-halves; 1024 threads = 16 waves; 1 block/CU,
// 4 waves/SIMD guaranteed co-resident. Block: rows [mt*64,+64) x cols [h*320,+320).
// Wave w: row-set rs=w>>2 (16 rows), col-chunk cc=w&3 (80 cols). No global atomics.
__global__ __launch_bounds__(1024, 4) void fused_vq_k(
    const float* __restrict__ x, const short* __restrict__ Wb,
    const float* __restrict__ W, const float* __restrict__ b,
    const float* __restrict__ codebook,
    float* __restrict__ partials,   // [NBLK][640]: counts(320) then probs(320)
    float* __restrict__ xq) {

    __shared__ short xs[BM][XS_STRIDE];      // 99328 B
    __shared__ float pacc[4][VSZ];           // per row-set prob col-sums
    __shared__ float cnt_f[VSZ];
    __shared__ float wmax[BM][4];
    __shared__ int   warg[BM][4];
    __shared__ float ssum[BM][4];
    __shared__ float rmax_s[BM];
    __shared__ int   rarg_s[BM];
    __shared__ int   cnt_s[BM];
    __shared__ int   list_s[BM][16];
    __shared__ int   code_s[BM];
    __shared__ int   work_s[BM];
    __shared__ int   nwork_s;

    const int tid   = threadIdx.x;
    const int lane  = tid & 63;
    const int w     = tid >> 6;       // wave 0..15
    const int l15   = lane & 15;
    const int l4    = lane >> 4;      // 0..3
    const int mt    = (int)blockIdx.x >> 1;
    const int h     = (int)blockIdx.x & 1;      // group
    const int row0  = mt * BM;
    const int rs    = w >> 2;         // row-set 0..3
    const int cc    = w & 3;          // col-chunk 0..3
    const int rbase = rs * 16;
    const int nf0   = h * 20 + cc * 5;

    for (int i = tid; i < VSZ; i += 1024) cnt_f[i] = 0.f;
    if (tid < BM) cnt_s[tid] = 0;
    if (tid == 0) nwork_s = 0;

    // ---- stage x tile as bf16: 64 rows x 768 k ----
    {
        const int srow = tid >> 4;
        const int sk   = (tid & 15) * 4;
        const float* xp = x + (size_t)(row0 + srow) * KDIM + sk;
#pragma unroll
        for (int t = 0; t < 12; ++t) {
            const float4 v = *(const float4*)(xp + t * 64);
            const short t0 = f2bf(v.x), t1 = f2bf(v.y), t2 = f2bf(v.z), t3 = f2bf(v.w);
            const int lo = (t0 & 0xffff) | (t1 << 16);
            const int hi = (t2 & 0xffff) | (t3 << 16);
            *(int2*)&xs[srow][t * 64 + sk] = make_int2(lo, hi);
        }
    }

    // packed-B offsets (shorts): frag (nf0+n, kb) at ((nf0+n)*1536 + lane)*8 + kb*512
    int boff[5];
#pragma unroll
    for (int n = 0; n < 5; ++n) boff[n] = ((nf0 + n) * 1536 + lane) * 8;

    f32x4 acc[5];
#pragma unroll
    for (int n = 0; n < 5; ++n) acc[n] = (f32x4){0.f, 0.f, 0.f, 0.f};

    // depth-3 register pipeline over 24 k-blocks of 32
    bf16x8 c0[5], c1[5], c2[5];
    LOADB(c0, 0);
    LOADB(c1, 1);
    LOADB(c2, 2);

    __syncthreads();   // x tile ready

#pragma unroll 1
    for (int kb = 0; kb < NKB; kb += 3) {
        DOMFMA(c0, kb);
        if (kb + 3 < NKB) { LOADB(c0, kb + 3); __builtin_amdgcn_sched_barrier(0); }
        DOMFMA(c1, kb + 1);
        if (kb + 4 < NKB) { LOADB(c1, kb + 4); __builtin_amdgcn_sched_barrier(0); }
        DOMFMA(c2, kb + 2);
        if (kb + 5 < NKB) { LOADB(c2, kb + 5); __builtin_amdgcn_sched_barrier(0); }
    }

    // bias (zeros in this problem, kept exact)
#pragma unroll
    for (int n = 0; n < 5; ++n) {
        const float bv = b[(nf0 + n) * 16 + l15];
#pragma unroll
        for (int r = 0; r < 4; ++r) acc[n][r] += bv;
    }

    // E1: wave-local per-row max/argmax over this wave's 80 cols
    // rows: rbase + l4*4 + r ; cols: (nf0+n)*16 + l15 (global col incl. group)
    float m4[4]; int a4[4];
#pragma unroll
    for (int r = 0; r < 4; ++r) { m4[r] = -3.4e38f; a4[r] = 0x7fffffff; }
#pragma unroll
    for (int n = 0; n < 5; ++n) {
        const int col = (nf0 + n) * 16 + l15;
#pragma unroll
        for (int r = 0; r < 4; ++r) {
            const float v = acc[n][r];
            if (v > m4[r]) { m4[r] = v; a4[r] = col; }
        }
    }
#pragma unroll
    for (int off = 8; off >= 1; off >>= 1)
#pragma unroll
        for (int r = 0; r < 4; ++r) {
            const float om = __shfl_xor(m4[r], off);
            const int   oa = __shfl_xor(a4[r], off);
            if (om > m4[r] || (om == m4[r] && oa < a4[r])) { m4[r] = om; a4[r] = oa; }
        }
    if (l15 == 0)
#pragma unroll
        for (int r = 0; r < 4; ++r) {
            const int row = rbase + l4 * 4 + r;
            wmax[row][cc] = m4[r];
            warg[row][cc] = a4[r];
        }
    __syncthreads();

    // E2a: combine 4 col-chunks -> row max over 320
    if (tid < BM) {
        float m = -3.4e38f; int c = 0x7fffffff;
#pragma unroll
        for (int q = 0; q < 4; ++q) {
            const float mq = wmax[tid][q];
            const int   cq = warg[tid][q];
            if (mq > m || (mq == m && cq < c)) { m = mq; c = cq; }
        }
        rmax_s[tid] = m;
        rarg_s[tid] = c;
    }
    __syncthreads();

    // E2b: candidate scan + exp + denominator partials
    float rm[4];
#pragma unroll
    for (int r = 0; r < 4; ++r) rm[r] = rmax_s[rbase + l4 * 4 + r];
    float sden[4] = {0.f, 0.f, 0.f, 0.f};
#pragma unroll
    for (int n = 0; n < 5; ++n) {
        const int col = (nf0 + n) * 16 + l15;
#pragma unroll
        for (int r = 0; r < 4; ++r) {
            const float v = acc[n][r];
            if (v > rm[r] - MARGIN) {
                const int row = rbase + l4 * 4 + r;
                const int idx = atomicAdd(&cnt_s[row], 1);
                if (idx < 16) list_s[row][idx] = col;
            }
            const float e = __expf(v - rm[r]);
            acc[n][r] = e;
            sden[r] += e;
        }
    }
#pragma unroll
    for (int off = 8; off >= 1; off >>= 1)
#pragma unroll
        for (int r = 0; r < 4; ++r) sden[r] += __shfl_xor(sden[r], off);
    if (l15 == 0)
#pragma unroll
        for (int r = 0; r < 4; ++r) ssum[rbase + l4 * 4 + r][cc] = sden[r];
    __syncthreads();

    // E3: single-candidate fast path; multi-candidate -> worklist
    if (tid < BM) {
        if (cnt_s[tid] <= 1) {
            code_s[tid] = rarg_s[tid];
        } else {
            const int wi = atomicAdd(&nwork_s, 1);
            work_s[wi] = tid;
        }
    }

    // E5: softmax column sums -> pacc[rs][v] (plain stores: (rs,cc) waves own disjoint slots)
    float inv[4];
#pragma unroll
    for (int r = 0; r < 4; ++r) {
        const int row = rbase + l4 * 4 + r;
        inv[r] = 1.f / (ssum[row][0] + ssum[row][1] + ssum[row][2] + ssum[row][3]);
    }
#pragma unroll
    for (int n = 0; n < 5; ++n) {
        float pc = 0.f;
#pragma unroll
        for (int r = 0; r < 4; ++r) pc += acc[n][r] * inv[r];
        pc += __shfl_xor(pc, 16);
        pc += __shfl_xor(pc, 32);
        if (l4 == 0) pacc[rs][(nf0 + n) * 16 + l15 - h * VSZ] = pc;
    }
    __syncthreads();

    // E4: fp32-exact refinement, one wave per pending row
    const int nwork = nwork_s;
    for (int it = w; it < nwork; it += 16) {
        const int row  = work_s[it];
        const int grow = row0 + row;
        const int nc   = min(cnt_s[row], 16);
        float bestv = -3.4e38f; int bestc = 0x7fffffff;
        for (int ci = 0; ci < nc; ++ci) {
            const int col = list_s[row][ci];
            float p = 0.f;
            for (int j = lane; j < KDIM; j += 64)
                p += x[(size_t)grow * KDIM + j] * W[(size_t)col * KDIM + j];
#pragma unroll
            for (int off = 32; off >= 1; off >>= 1) p += __shfl_xor(p, off);
            p += b[col];
            if (p > bestv || (p == bestv && col < bestc)) { bestv = p; bestc = col; }
        }
        if (lane == 0) code_s[row] = bestc;
    }
    __syncthreads();

    // counts histogram in LDS
    if (tid < BM) atomicAdd(&cnt_f[code_s[tid] - h * VSZ], 1.f);

    // E7: gather xq for this block's 64 rows, its group's 128-dim half
#pragma unroll
    for (int u = 0; u < 2; ++u) {
        const int f   = tid + u * 1024;     // float4 index 0..2047
        const int row = f >> 5;
        const int d4  = (f & 31) * 4;
        const int k   = code_s[row];        // global col = codebook row
        const float4 v = *(const float4*)(codebook + (size_t)k * DSZ + d4);
        *(float4*)(xq + (size_t)(row0 + row) * (GSZ * DSZ) + h * DSZ + d4) = v;
    }
    __syncthreads();

    // per-block partials: counts(320) then probs(320), coalesced
    float* myp = partials + (size_t)blockIdx.x * NCOL;
    for (int i = tid; i < NCOL; i += 1024)
        myp[i] = (i < VSZ) ? cnt_f[i]
                           : (pacc[0][i - VSZ] + pacc[1][i - VSZ] +
                              pacc[2][i - VSZ] + pacc[3][i - VSZ]);
}

// ---------------- reduce partials + perplexities + constant ----------------
__global__ __launch_bounds__(640) void red_fin_k(const float* __restrict__ partials,
                                                 float* __restrict__ out_scalars) {
    __shared__ float se_c[GSZ], se_p[GSZ];
    const int t = threadIdx.x;   // 0..639 = global column
    if (t < GSZ) { se_c[t] = 0.f; se_p[t] = 0.f; }
    __syncthreads();
    const int g = t / VSZ;
    const int v = t - g * VSZ;
    float sc = 0.f, sp = 0.f;
#pragma unroll 8
    for (int m = 0; m < NMT; ++m) {
        const float* p = partials + ((size_t)m * 2 + g) * NCOL;
        sc += p[v];
        sp += p[VSZ + v];
    }
    const float hp = sc * (1.f / (float)NROWS);
    const float ap = sp * (1.f / (float)NROWS);
    float tc = hp * logf(hp + 1e-7f);
    float tp = ap * logf(ap + 1e-7f);
#pragma unroll
    for (int off = 32; off >= 1; off >>= 1) {
        tc += __shfl_xor(tc, off);
        tp += __shfl_xor(tp, off);
    }
    if ((t & 63) == 0) { atomicAdd(&se_c[g], tc); atomicAdd(&se_p[g], tp); }
    __syncthreads();
    if (t == 0) {
        out_scalars[0] = (float)NCOL;
        out_scalars[1] = expf(-se_c[0]) + expf(-se_c[1]);
        out_scalars[2] = expf(-se_p[0]) + expf(-se_p[1]);
    }
}

extern "C" void kernel_launch(void* const* d_in, const int* in_sizes, int n_in,
                              void* d_out, int out_size, void* d_ws, size_t ws_size,
                              hipStream_t stream) {
    const float* x        = (const float*)d_in[0];
    const float* W        = (const float*)d_in[1];
    const float* b        = (const float*)d_in[2];
    const float* codebook = (const float*)d_in[3];
    float* out = (float*)d_out;

    short* Wb       = (short*)d_ws;                                   // 983,040 B
    float* partials = (float*)((char*)d_ws + 983040);                 // 256*640*4 = 655,360 B

    prep_w_k<<<dim3(120), dim3(512), 0, stream>>>(W, Wb);
    fused_vq_k<<<dim3(NBLK), dim3(1024), 0, stream>>>(x, Wb, W, b, codebook,
                                                      partials, out);
    red_fin_k<<<dim3(1), dim3(640), 0, stream>>>(partials, out + XQ_TOTAL);
}

// Round 8
// 63.910 us; speedup vs baseline: 1.5420x; 1.0031x over previous
//
#include <hip/hip_runtime.h>
#include <hip/hip_bf16.h>

#define NROWS 8192      // B*T
#define KDIM  768       // F_IN
#define VSZ   320       // V
#define GSZ   2         // G
#define NCOL  640       // G*V
#define DSZ   128       // D
#define BM    64        // rows per block
#define NMT   (NROWS / BM)             // 128 M-tiles
#define NBLK  (NMT * 2)                // 256 blocks (x2 group-halves)
#define NKB   24                       // K blocks of 32
#define XQ_TOTAL (NROWS * GSZ * DSZ)   // 2097152
#define MARGIN 1.5f
#define XS_STRIDE 776   // 768+8 shorts: 16B-aligned rows, 4-word bank skew

typedef __attribute__((ext_vector_type(8))) short bf16x8;
typedef __attribute__((ext_vector_type(4))) float f32x4;

static __device__ __forceinline__ short f2bf(float f) {
    union { __hip_bfloat16 h; short s; } u;
    u.h = __float2bfloat16(f);   // round-to-nearest-even
    return u.s;
}

static __device__ __forceinline__ void gload_lds16(const void* g, void* l) {
    __builtin_amdgcn_global_load_lds(
        (const __attribute__((address_space(1))) void*)g,
        (__attribute__((address_space(3))) void*)l, 16, 0, 0);
}

// ---------------- W f32 -> packed frag-major bf16 ----------------
// Wb: frag f = nf*24 + kb (nf = 16-col group 0..39, kb = 32-k block 0..23), 1KB each.
// (f, lane): col = nf*16 + (lane&15), k = kb*32 + (lane>>4)*8, 8 bf16 at byte lane*16.
__global__ __launch_bounds__(512) void prep_w_k(const float* __restrict__ W,
                                                short* __restrict__ Wb) {
    const int idx = blockIdx.x * 512 + threadIdx.x;   // 0..61439
    const int l   = idx & 63;
    const int f   = idx >> 6;
    const int nf  = f / NKB;
    const int kb  = f - nf * NKB;
    const int col = nf * 16 + (l & 15);
    const int k   = kb * 32 + (l >> 4) * 8;
    const float4 a = *(const float4*)(W + (size_t)col * KDIM + k);
    const float4 c = *(const float4*)(W + (size_t)col * KDIM + k + 4);
    bf16x8 r;
    r[0] = f2bf(a.x); r[1] = f2bf(a.y); r[2] = f2bf(a.z); r[3] = f2bf(a.w);
    r[4] = f2bf(c.x); r[5] = f2bf(c.y); r[6] = f2bf(c.z); r[7] = f2bf(c.w);
    *(bf16x8*)(Wb + (size_t)idx * 8) = r;
}

// ---------------- fused: LDS-staged-B MFMA GEMM + argmax + softmax + refine + gather ----------------
// grid 256 = 128 M-tiles x 2 group-halves; 1024 threads = 16 waves (rs 0..3 x cc 0..3).
// Block: rows [mt*64,+64) x cols [h*320,+320). B staged kb-by-kb into LDS double
// buffer via global_load_lds (read ONCE per block from L2); one barrier per kb.
__global__ __launch_bounds__(1024, 4) void fused_vq_k(
    const float* __restrict__ x, const short* __restrict__ Wb,
    const float* __restrict__ W, const float* __restrict__ b,
    const float* __restrict__ codebook,
    float* __restrict__ partials,   // [NBLK][640]: counts(320) then probs(320)
    float* __restrict__ xq) {

    __shared__ short xs[BM][XS_STRIDE];              // 99,328 B
    __shared__ __align__(16) char bs[2][20 * 1024];  // 40,960 B  B frag double-buffer
    __shared__ float pacc[4][VSZ];
    __shared__ float cnt_f[VSZ];
    __shared__ float wmax[BM][4];
    __shared__ int   warg[BM][4];
    __shared__ float ssum[BM][4];
    __shared__ float rmax_s[BM];
    __shared__ int   rarg_s[BM];
    __shared__ int   cnt_s[BM];
    __shared__ int   list_s[BM][16];
    __shared__ int   code_s[BM];
    __shared__ int   work_s[BM];
    __shared__ int   nwork_s;

    const int tid   = threadIdx.x;
    const int lane  = tid & 63;
    const int w     = tid >> 6;       // wave 0..15
    const int l15   = lane & 15;
    const int l4    = lane >> 4;      // 0..3
    const int mt    = (int)blockIdx.x >> 1;
    const int h     = (int)blockIdx.x & 1;      // group
    const int row0  = mt * BM;
    const int rs    = w >> 2;         // row-set 0..3 (16 rows each)
    const int cc    = w & 3;          // col-chunk 0..3 (80 cols each)
    const int rbase = rs * 16;
    const int nf0   = h * 20 + cc * 5;

    const char* WbB = (const char*)Wb;

    for (int i = tid; i < VSZ; i += 1024) cnt_f[i] = 0.f;
    if (tid < BM) cnt_s[tid] = 0;
    if (tid == 0) nwork_s = 0;

    // ---- issue B stage for kb=0 (frag f -> wave f%16; LDS dst wave-uniform) ----
#pragma unroll
    for (int f = w; f < 20; f += 16)
        gload_lds16(WbB + ((size_t)(h * 20 + f) * NKB + 0) * 1024 + lane * 16,
                    &bs[0][f * 1024]);

    // ---- stage x tile as bf16: 64 rows x 768 k ----
    {
        const int srow = tid >> 4;
        const int sk   = (tid & 15) * 4;
        const float* xp = x + (size_t)(row0 + srow) * KDIM + sk;
#pragma unroll
        for (int t = 0; t < 12; ++t) {
            const float4 v = *(const float4*)(xp + t * 64);
            const short t0 = f2bf(v.x), t1 = f2bf(v.y), t2 = f2bf(v.z), t3 = f2bf(v.w);
            const int lo = (t0 & 0xffff) | (t1 << 16);
            const int hi = (t2 & 0xffff) | (t3 << 16);
            *(int2*)&xs[srow][t * 64 + sk] = make_int2(lo, hi);
        }
    }

    f32x4 acc[5];
#pragma unroll
    for (int n = 0; n < 5; ++n) acc[n] = (f32x4){0.f, 0.f, 0.f, 0.f};

    __syncthreads();   // xs written, bs[0] landed (full waitcnt before barrier)

    // ---- K loop: one barrier per kb; stage next while computing current ----
#pragma unroll 1
    for (int kb = 0; kb < NKB; ++kb) {
        const int buf = kb & 1;
        if (kb + 1 < NKB) {
#pragma unroll
            for (int f = w; f < 20; f += 16)
                gload_lds16(WbB + ((size_t)(h * 20 + f) * NKB + (kb + 1)) * 1024 + lane * 16,
                            &bs[buf ^ 1][f * 1024]);
        }
        const bf16x8 a_ = *(const bf16x8*)&xs[rbase + l15][kb * 32 + l4 * 8];
        bf16x8 bf[5];
#pragma unroll
        for (int n = 0; n < 5; ++n)
            bf[n] = *(const bf16x8*)&bs[buf][(cc * 5 + n) * 1024 + lane * 16];
#pragma unroll
        for (int n = 0; n < 5; ++n)
            acc[n] = __builtin_amdgcn_mfma_f32_16x16x32_bf16(a_, bf[n], acc[n], 0, 0, 0);
        __syncthreads();   // drains this wave's gloads; all waves done reading buf
    }

    // bias (zeros in this problem, kept exact)
#pragma unroll
    for (int n = 0; n < 5; ++n) {
        const float bv = b[(nf0 + n) * 16 + l15];
#pragma unroll
        for (int r = 0; r < 4; ++r) acc[n][r] += bv;
    }

    // E1: wave-local per-row max/argmax over this wave's 80 cols
    // rows: rbase + l4*4 + r ; cols: (nf0+n)*16 + l15 (global col incl. group)
    float m4[4]; int a4[4];
#pragma unroll
    for (int r = 0; r < 4; ++r) { m4[r] = -3.4e38f; a4[r] = 0x7fffffff; }
#pragma unroll
    for (int n = 0; n < 5; ++n) {
        const int col = (nf0 + n) * 16 + l15;
#pragma unroll
        for (int r = 0; r < 4; ++r) {
            const float v = acc[n][r];
            if (v > m4[r]) { m4[r] = v; a4[r] = col; }
        }
    }
#pragma unroll
    for (int off = 8; off >= 1; off >>= 1)
#pragma unroll
        for (int r = 0; r < 4; ++r) {
            const float om = __shfl_xor(m4[r], off);
            const int   oa = __shfl_xor(a4[r], off);
            if (om > m4[r] || (om == m4[r] && oa < a4[r])) { m4[r] = om; a4[r] = oa; }
        }
    if (l15 == 0)
#pragma unroll
        for (int r = 0; r < 4; ++r) {
            const int row = rbase + l4 * 4 + r;
            wmax[row][cc] = m4[r];
            warg[row][cc] = a4[r];
        }
    __syncthreads();

    // E2a: combine 4 col-chunks -> row max over 320
    if (tid < BM) {
        float m = -3.4e38f; int c = 0x7fffffff;
#pragma unroll
        for (int q = 0; q < 4; ++q) {
            const float mq = wmax[tid][q];
            const int   cq = warg[tid][q];
            if (mq > m || (mq == m && cq < c)) { m = mq; c = cq; }
        }
        rmax_s[tid] = m;
        rarg_s[tid] = c;
    }
    __syncthreads();

    // E2b: candidate scan + exp + denominator partials
    float rm[4];
#pragma unroll
    for (int r = 0; r < 4; ++r) rm[r] = rmax_s[rbase + l4 * 4 + r];
    float sden[4] = {0.f, 0.f, 0.f, 0.f};
#pragma unroll
    for (int n = 0; n < 5; ++n) {
        const int col = (nf0 + n) * 16 + l15;
#pragma unroll
        for (int r = 0; r < 4; ++r) {
            const float v = acc[n][r];
            if (v > rm[r] - MARGIN) {
                const int row = rbase + l4 * 4 + r;
                const int idx = atomicAdd(&cnt_s[row], 1);
                if (idx < 16) list_s[row][idx] = col;
            }
            const float e = __expf(v - rm[r]);
            acc[n][r] = e;
            sden[r] += e;
        }
    }
#pragma unroll
    for (int off = 8; off >= 1; off >>= 1)
#pragma unroll
        for (int r = 0; r < 4; ++r) sden[r] += __shfl_xor(sden[r], off);
    if (l15 == 0)
#pragma unroll
        for (int r = 0; r < 4; ++r) ssum[rbase + l4 * 4 + r][cc] = sden[r];
    __syncthreads();

    // E3: single-candidate fast path; multi-candidate -> worklist
    if (tid < BM) {
        if (cnt_s[tid] <= 1) {
            code_s[tid] = rarg_s[tid];
        } else {
            const int wi = atomicAdd(&nwork_s, 1);
            work_s[wi] = tid;
        }
    }

    // E5: softmax column sums -> pacc[rs][v] (plain stores: (rs,cc) waves own disjoint slots)
    float inv[4];
#pragma unroll
    for (int r = 0; r < 4; ++r) {
        const int row = rbase + l4 * 4 + r;
        inv[r] = 1.f / (ssum[row][0] + ssum[row][1] + ssum[row][2] + ssum[row][3]);
    }
#pragma unroll
    for (int n = 0; n < 5; ++n) {
        float pc = 0.f;
#pragma unroll
        for (int r = 0; r < 4; ++r) pc += acc[n][r] * inv[r];
        pc += __shfl_xor(pc, 16);
        pc += __shfl_xor(pc, 32);
        if (l4 == 0) pacc[rs][(nf0 + n) * 16 + l15 - h * VSZ] = pc;
    }
    __syncthreads();

    // E4: fp32-exact refinement, one wave per pending row
    const int nwork = nwork_s;
    for (int it = w; it < nwork; it += 16) {
        const int row  = work_s[it];
        const int grow = row0 + row;
        const int nc   = min(cnt_s[row], 16);
        float bestv = -3.4e38f; int bestc = 0x7fffffff;
        for (int ci = 0; ci < nc; ++ci) {
            const int col = list_s[row][ci];
            float p = 0.f;
            for (int j = lane; j < KDIM; j += 64)
                p += x[(size_t)grow * KDIM + j] * W[(size_t)col * KDIM + j];
#pragma unroll
            for (int off = 32; off >= 1; off >>= 1) p += __shfl_xor(p, off);
            p += b[col];
            if (p > bestv || (p == bestv && col < bestc)) { bestv = p; bestc = col; }
        }
        if (lane == 0) code_s[row] = bestc;
    }
    __syncthreads();

    // counts histogram in LDS
    if (tid < BM) atomicAdd(&cnt_f[code_s[tid] - h * VSZ], 1.f);

    // E7: gather xq for this block's 64 rows, its group's 128-dim half
#pragma unroll
    for (int u = 0; u < 2; ++u) {
        const int f   = tid + u * 1024;     // float4 index 0..2047
        const int row = f >> 5;
        const int d4  = (f & 31) * 4;
        const int k   = code_s[row];        // global col = codebook row
        const float4 v = *(const float4*)(codebook + (size_t)k * DSZ + d4);
        *(float4*)(xq + (size_t)(row0 + row) * (GSZ * DSZ) + h * DSZ + d4) = v;
    }
    __syncthreads();

    // per-block partials: counts(320) then probs(320), coalesced
    float* myp = partials + (size_t)blockIdx.x * NCOL;
    for (int i = tid; i < NCOL; i += 1024)
        myp[i] = (i < VSZ) ? cnt_f[i]
                           : (pacc[0][i - VSZ] + pacc[1][i - VSZ] +
                              pacc[2][i - VSZ] + pacc[3][i - VSZ]);
}

// ---------------- reduce partials + perplexities + constant ----------------
__global__ __launch_bounds__(640) void red_fin_k(const float* __restrict__ partials,
                                                 float* __restrict__ out_scalars) {
    __shared__ float se_c[GSZ], se_p[GSZ];
    const int t = threadIdx.x;   // 0..639 = global column
    if (t < GSZ) { se_c[t] = 0.f; se_p[t] = 0.f; }
    __syncthreads();
    const int g = t / VSZ;
    const int v = t - g * VSZ;
    float sc = 0.f, sp = 0.f;
#pragma unroll 8
    for (int m = 0; m < NMT; ++m) {
        const float* p = partials + ((size_t)m * 2 + g) * NCOL;
        sc += p[v];
        sp += p[VSZ + v];
    }
    const float hp = sc * (1.f / (float)NROWS);
    const float ap = sp * (1.f / (float)NROWS);
    float tc = hp * logf(hp + 1e-7f);
    float tp = ap * logf(ap + 1e-7f);
#pragma unroll
    for (int off = 32; off >= 1; off >>= 1) {
        tc += __shfl_xor(tc, off);
        tp += __shfl_xor(tp, off);
    }
    if ((t & 63) == 0) { atomicAdd(&se_c[g], tc); atomicAdd(&se_p[g], tp); }
    __syncthreads();
    if (t == 0) {
        out_scalars[0] = (float)NCOL;
        out_scalars[1] = expf(-se_c[0]) + expf(-se_c[1]);
        out_scalars[2] = expf(-se_p[0]) + expf(-se_p[1]);
    }
}

extern "C" void kernel_launch(void* const* d_in, const int* in_sizes, int n_in,
                              void* d_out, int out_size, void* d_ws, size_t ws_size,
                              hipStream_t stream) {
    const float* x        = (const float*)d_in[0];
    const float* W        = (const float*)d_in[1];
    const float* b        = (const float*)d_in[2];
    const float* codebook = (const float*)d_in[3];
    float* out = (float*)d_out;

    short* Wb       = (short*)d_ws;                                   // 983,040 B
    float* partials = (float*)((char*)d_ws + 983040);                 // 256*640*4 = 655,360 B

    prep_w_k<<<dim3(120), dim3(512), 0, stream>>>(W, Wb);
    fused_vq_k<<<dim3(NBLK), dim3(1024), 0, stream>>>(x, Wb, W, b, codebook,
                                                      partials, out);
    red_fin_k<<<dim3(1), dim3(640), 0, stream>>>(partials, out + XQ_TOTAL);
}